// Round 3
// baseline (459.082 us; speedup 1.0000x reference)
//
#include <hip/hip_runtime.h>

// DIAGNOSTIC ROUND: identical structure to Round 2, but stage1 streams W
// FOUR times (K-rotated per pass to defeat load CSE; final *0.25f is exact).
// Purpose: (a) discriminate "fixed harness overhead" vs "slow kernel" via
// dur_us delta; (b) push stage1 above the ~158 µs top-5 profile cutoff so
// its FETCH_SIZE / hbm_gbps become directly visible.

#define IN_LEN   8192
#define OUT_LEN  8192
#define SPLITS   128
#define K_CHUNK  (IN_LEN / SPLITS)     // 64
#define THREADS  256
#define NCOL4    (OUT_LEN / 4)         // 2048 float4 columns
#define PASSES   4

__global__ __launch_bounds__(THREADS, 4)
void matvec_stage1(const float* __restrict__ x,
                   const float* __restrict__ W,
                   float* __restrict__ ws) {
    const int col4  = blockIdx.x * THREADS + threadIdx.x;  // float4 column
    const int kbase = blockIdx.y * K_CHUNK;

    const float4* __restrict__ W4 = (const float4*)W;
    float4 acc = make_float4(0.f, 0.f, 0.f, 0.f);

    for (int p = 0; p < PASSES; ++p) {
        const int rot = p * (K_CHUNK / PASSES);            // rotate start per pass
#pragma unroll 16
        for (int i = 0; i < K_CHUNK; ++i) {
            const int   k  = (i + rot) & (K_CHUNK - 1);
            const float xs = x[kbase + k];                 // wave-uniform -> s_load
            const float4 w = W4[(size_t)(kbase + k) * NCOL4 + col4];
            acc.x += xs * w.x;
            acc.y += xs * w.y;
            acc.z += xs * w.z;
            acc.w += xs * w.w;
        }
    }

    // Each pass summed the same 64 products -> acc = 4*S; *0.25f is exact.
    float4 r = make_float4(acc.x * 0.25f, acc.y * 0.25f,
                           acc.z * 0.25f, acc.w * 0.25f);
    ((float4*)ws)[(size_t)blockIdx.y * NCOL4 + col4] = r;
}

// Reduce SPLITS partials per column + bias (unchanged from Round 2).
__global__ __launch_bounds__(THREADS)
void matvec_stage2(const float* __restrict__ ws,
                   const float* __restrict__ b,
                   float* __restrict__ out) {
    const int c   = threadIdx.x & 63;        // column within block
    const int g   = threadIdx.x >> 6;        // split-group 0..3
    const int col = blockIdx.x * 64 + c;

    float s = 0.f;
#pragma unroll 8
    for (int sp = g; sp < SPLITS; sp += 4)   // lanes read consecutive cols: coalesced
        s += ws[(size_t)sp * OUT_LEN + col];

    __shared__ float red[4][64];
    red[g][c] = s;
    __syncthreads();

    if (threadIdx.x < 64) {
        const int j = blockIdx.x * 64 + threadIdx.x;
        out[j] = red[0][threadIdx.x] + red[1][threadIdx.x] +
                 red[2][threadIdx.x] + red[3][threadIdx.x] + b[j];
    }
}

extern "C" void kernel_launch(void* const* d_in, const int* in_sizes, int n_in,
                              void* d_out, int out_size, void* d_ws, size_t ws_size,
                              hipStream_t stream) {
    const float* x = (const float*)d_in[0];   // (1, 8192)
    const float* W = (const float*)d_in[1];   // (8192, 8192) row-major
    const float* b = (const float*)d_in[2];   // (8192,)
    float* out = (float*)d_out;               // (1, 8192)
    float* ws  = (float*)d_ws;                // >= SPLITS*OUT_LEN*4 = 4 MB

    dim3 grid1(NCOL4 / THREADS, SPLITS);      // (8, 128) = 1024 blocks
    matvec_stage1<<<grid1, dim3(THREADS), 0, stream>>>(x, W, ws);

    matvec_stage2<<<dim3(OUT_LEN / 64), dim3(THREADS), 0, stream>>>(ws, b, out);
}

// Round 4
// 367.394 us; speedup vs baseline: 1.2496x; 1.2496x over previous
//
#include <hip/hip_runtime.h>

// out[1,8192] = x[1,8192] @ W[8192,8192] + b[8192]   (all fp32)
// R4 theory: R2/R3 stage1 ran ~2.3 TB/s (37% of achievable) due to
// (a) per-iteration scalar x-load lgkmcnt drains inside the vmcnt clause,
// (b) marginal MLP (11 waves/CU, ~5 loads in flight).
// Fix: x staged in LDS once per block; SPLITS=256 -> 2048 blocks = 32
// waves/CU with VGPRs capped at 64 via __launch_bounds__(256,8).

#define IN_LEN   8192
#define OUT_LEN  8192
#define SPLITS   256
#define K_CHUNK  (IN_LEN / SPLITS)     // 32
#define THREADS  256
#define NCOL4    (OUT_LEN / 4)         // 2048 float4 columns

__global__ __launch_bounds__(THREADS, 8)
void matvec_stage1(const float* __restrict__ x,
                   const float* __restrict__ W,
                   float* __restrict__ ws) {
    const int col4  = blockIdx.x * THREADS + threadIdx.x;  // float4 column
    const int kbase = blockIdx.y * K_CHUNK;

    // Stage x-chunk to LDS once; inner-loop x reads become ds_read
    // broadcasts (same addr across lanes -> conflict-free), fully
    // overlapped with the global-load clause. No s_load/lgkmcnt drains.
    __shared__ float xs[K_CHUNK];
    if (threadIdx.x < K_CHUNK) xs[threadIdx.x] = x[kbase + threadIdx.x];
    __syncthreads();

    const float4* __restrict__ W4 = (const float4*)W;
    float4 acc = make_float4(0.f, 0.f, 0.f, 0.f);

#pragma unroll
    for (int i = 0; i < K_CHUNK; ++i) {
        const float  xv = xs[i];
        const float4 w  = W4[(size_t)(kbase + i) * NCOL4 + col4];
        acc.x += xv * w.x;
        acc.y += xv * w.y;
        acc.z += xv * w.z;
        acc.w += xv * w.w;
    }

    // partial layout: ws[split][OUT_LEN], coalesced float4 store
    ((float4*)ws)[(size_t)blockIdx.y * NCOL4 + col4] = acc;
}

// Reduce SPLITS partials per column + bias.
__global__ __launch_bounds__(THREADS)
void matvec_stage2(const float* __restrict__ ws,
                   const float* __restrict__ b,
                   float* __restrict__ out) {
    const int c   = threadIdx.x & 63;        // column within block
    const int g   = threadIdx.x >> 6;        // split-group 0..3
    const int col = blockIdx.x * 64 + c;

    float s = 0.f;
#pragma unroll 8
    for (int sp = g; sp < SPLITS; sp += 4)   // lanes read consecutive cols: coalesced
        s += ws[(size_t)sp * OUT_LEN + col];

    __shared__ float red[4][64];
    red[g][c] = s;
    __syncthreads();

    if (threadIdx.x < 64) {
        const int j = blockIdx.x * 64 + threadIdx.x;
        out[j] = red[0][threadIdx.x] + red[1][threadIdx.x] +
                 red[2][threadIdx.x] + red[3][threadIdx.x] + b[j];
    }
}

extern "C" void kernel_launch(void* const* d_in, const int* in_sizes, int n_in,
                              void* d_out, int out_size, void* d_ws, size_t ws_size,
                              hipStream_t stream) {
    const float* x = (const float*)d_in[0];   // (1, 8192)
    const float* W = (const float*)d_in[1];   // (8192, 8192) row-major
    const float* b = (const float*)d_in[2];   // (8192,)
    float* out = (float*)d_out;               // (1, 8192)
    float* ws  = (float*)d_ws;                // >= SPLITS*OUT_LEN*4 = 8 MB

    dim3 grid1(NCOL4 / THREADS, SPLITS);      // (8, 256) = 2048 blocks, 8/CU
    matvec_stage1<<<grid1, dim3(THREADS), 0, stream>>>(x, W, ws);

    matvec_stage2<<<dim3(OUT_LEN / 64), dim3(THREADS), 0, stream>>>(ws, b, out);
}